// Round 2
// baseline (1321.097 us; speedup 1.0000x reference)
//
#include <hip/hip_runtime.h>
#include <math.h>

// Problem constants: B=2, N=2048, DIM=1024, H=16, D=64
// tokens M = B*N = 4096; qkv cols = 3072

// ---------------------------------------------------------------------------
// GEMM: C_logical[M][NC] = A[M][1024] @ W[NC][1024]^T + bias[NC]
// Tile 64x64, BK=16, 256 threads, 4x4 register tile per thread.
// LDS tiles stored K-major ([kk][row]) so fragment reads are float4.
// gemm_qkv scatters into q/k/v [B,H,N,D]; gemm_proj writes row-major C.
// ---------------------------------------------------------------------------

__global__ __launch_bounds__(256) void gemm_qkv_kernel(
    const float* __restrict__ A, const float* __restrict__ W,
    const float* __restrict__ bias, float* __restrict__ Qp,
    float* __restrict__ Kp, float* __restrict__ Vp)
{
    __shared__ __align__(16) float Ast[16][68];
    __shared__ __align__(16) float Wst[16][68];
    const int t = threadIdx.x;
    const int tx = t & 15, ty = t >> 4;
    const int m0 = blockIdx.y * 64;
    const int n0 = blockIdx.x * 64;
    float acc[4][4] = {};

    for (int k0 = 0; k0 < 1024; k0 += 16) {
#pragma unroll
        for (int i = 0; i < 4; i++) {
            int idx = i * 256 + t;
            int r = idx >> 4, c = idx & 15;
            Ast[c][r] = A[(size_t)(m0 + r) * 1024 + k0 + c];
            Wst[c][r] = W[(size_t)(n0 + r) * 1024 + k0 + c];
        }
        __syncthreads();
#pragma unroll
        for (int kk = 0; kk < 16; kk++) {
            float4 a4 = *reinterpret_cast<const float4*>(&Ast[kk][ty * 4]);
            float4 b4 = *reinterpret_cast<const float4*>(&Wst[kk][tx * 4]);
            float a[4] = {a4.x, a4.y, a4.z, a4.w};
            float b[4] = {b4.x, b4.y, b4.z, b4.w};
#pragma unroll
            for (int i = 0; i < 4; i++)
#pragma unroll
                for (int j = 0; j < 4; j++)
                    acc[i][j] = fmaf(a[i], b[j], acc[i][j]);
        }
        __syncthreads();
    }

#pragma unroll
    for (int i = 0; i < 4; i++) {
        int row = m0 + ty * 4 + i;
        int bb = row >> 11, n = row & 2047;
#pragma unroll
        for (int j = 0; j < 4; j++) {
            int col = n0 + tx * 4 + j;
            float val = acc[i][j] + bias[col];
            int which = col >> 10;
            int rem = col & 1023;
            int h = rem >> 6, d = rem & 63;
            float* dst = (which == 0) ? Qp : ((which == 1) ? Kp : Vp);
            dst[((size_t)((bb * 16 + h) * 2048 + n)) * 64 + d] = val;
        }
    }
}

__global__ __launch_bounds__(256) void gemm_proj_kernel(
    const float* __restrict__ A, const float* __restrict__ W,
    const float* __restrict__ bias, float* __restrict__ C)
{
    __shared__ __align__(16) float Ast[16][68];
    __shared__ __align__(16) float Wst[16][68];
    const int t = threadIdx.x;
    const int tx = t & 15, ty = t >> 4;
    const int m0 = blockIdx.y * 64;
    const int n0 = blockIdx.x * 64;
    float acc[4][4] = {};

    for (int k0 = 0; k0 < 1024; k0 += 16) {
#pragma unroll
        for (int i = 0; i < 4; i++) {
            int idx = i * 256 + t;
            int r = idx >> 4, c = idx & 15;
            Ast[c][r] = A[(size_t)(m0 + r) * 1024 + k0 + c];
            Wst[c][r] = W[(size_t)(n0 + r) * 1024 + k0 + c];
        }
        __syncthreads();
#pragma unroll
        for (int kk = 0; kk < 16; kk++) {
            float4 a4 = *reinterpret_cast<const float4*>(&Ast[kk][ty * 4]);
            float4 b4 = *reinterpret_cast<const float4*>(&Wst[kk][tx * 4]);
            float a[4] = {a4.x, a4.y, a4.z, a4.w};
            float b[4] = {b4.x, b4.y, b4.z, b4.w};
#pragma unroll
            for (int i = 0; i < 4; i++)
#pragma unroll
                for (int j = 0; j < 4; j++)
                    acc[i][j] = fmaf(a[i], b[j], acc[i][j]);
        }
        __syncthreads();
    }

#pragma unroll
    for (int i = 0; i < 4; i++) {
        int row = m0 + ty * 4 + i;
#pragma unroll
        for (int j = 0; j < 4; j++) {
            int col = n0 + tx * 4 + j;
            C[(size_t)row * 1024 + col] = acc[i][j] + bias[col];
        }
    }
}

// ---------------------------------------------------------------------------
// Flash attention, f32. grid = (N/64, H, B), block = 256.
// Each block: 64 q-rows. Iterate 32 K-tiles of 64 keys, online softmax.
// Thread (tx,ty) owns S/O sub-tile rows ty*4+i, cols tx*4+j.
// ---------------------------------------------------------------------------
__global__ __launch_bounds__(256) void attn_kernel(
    const float* __restrict__ Q, const float* __restrict__ K,
    const float* __restrict__ V, float* __restrict__ O)
{
    __shared__ __align__(16) float Qst[64][68];  // [d][qrow]
    __shared__ __align__(16) float Kst[64][68];  // [d][kcol]
    __shared__ __align__(16) float Vs[64][68];   // [krow][d]
    __shared__ __align__(16) float Ps[64][68];   // [qrow][kcol]

    const int t = threadIdx.x;
    const int tx = t & 15, ty = t >> 4;
    const int q0 = blockIdx.x * 64;
    const int h = blockIdx.y, bb = blockIdx.z;
    const int bh = bb * 16 + h;
    const float* Qb = Q + (size_t)bh * 2048 * 64;
    const float* Kb = K + (size_t)bh * 2048 * 64;
    const float* Vb = V + (size_t)bh * 2048 * 64;

    // load Q tile transposed ([d][row])
#pragma unroll
    for (int i = 0; i < 16; i++) {
        int idx = i * 256 + t;
        int r = idx >> 6, c = idx & 63;
        Qst[c][r] = Qb[(size_t)(q0 + r) * 64 + c];
    }

    float m_i[4], l_i[4], o[4][4] = {};
#pragma unroll
    for (int i = 0; i < 4; i++) { m_i[i] = -INFINITY; l_i[i] = 0.0f; }
    __syncthreads();

    for (int kt = 0; kt < 32; kt++) {
        const int k0 = kt * 64;
#pragma unroll
        for (int i = 0; i < 16; i++) {
            int idx = i * 256 + t;
            int r = idx >> 6, c = idx & 63;
            Kst[c][r] = Kb[(size_t)(k0 + r) * 64 + c];
            Vs[r][c]  = Vb[(size_t)(k0 + r) * 64 + c];
        }
        __syncthreads();

        // S = Q @ K^T (4x4 per thread)
        float s[4][4] = {};
#pragma unroll 16
        for (int kd = 0; kd < 64; kd++) {
            float4 a4 = *reinterpret_cast<const float4*>(&Qst[kd][ty * 4]);
            float4 b4 = *reinterpret_cast<const float4*>(&Kst[kd][tx * 4]);
            float a[4] = {a4.x, a4.y, a4.z, a4.w};
            float b[4] = {b4.x, b4.y, b4.z, b4.w};
#pragma unroll
            for (int i = 0; i < 4; i++)
#pragma unroll
                for (int j = 0; j < 4; j++)
                    s[i][j] = fmaf(a[i], b[j], s[i][j]);
        }

        // online softmax update (rows reduced across the 16 tx lanes)
#pragma unroll
        for (int i = 0; i < 4; i++) {
#pragma unroll
            for (int j = 0; j < 4; j++) s[i][j] *= 0.125f;
            float tm = fmaxf(fmaxf(s[i][0], s[i][1]), fmaxf(s[i][2], s[i][3]));
#pragma unroll
            for (int sh = 1; sh < 16; sh <<= 1)
                tm = fmaxf(tm, __shfl_xor(tm, sh));
            float mnew = fmaxf(m_i[i], tm);
            float al = expf(m_i[i] - mnew);
            float ps = 0.0f;
#pragma unroll
            for (int j = 0; j < 4; j++) {
                float p = expf(s[i][j] - mnew);
                Ps[ty * 4 + i][tx * 4 + j] = p;
                ps += p;
            }
#pragma unroll
            for (int sh = 1; sh < 16; sh <<= 1)
                ps += __shfl_xor(ps, sh);
            l_i[i] = l_i[i] * al + ps;
            m_i[i] = mnew;
#pragma unroll
            for (int j = 0; j < 4; j++) o[i][j] *= al;
        }
        __syncthreads();

        // O += P @ V
#pragma unroll 16
        for (int kk = 0; kk < 64; kk++) {
            float4 b4 = *reinterpret_cast<const float4*>(&Vs[kk][tx * 4]);
            float b[4] = {b4.x, b4.y, b4.z, b4.w};
            float a[4];
#pragma unroll
            for (int i = 0; i < 4; i++) a[i] = Ps[ty * 4 + i][kk];
#pragma unroll
            for (int i = 0; i < 4; i++)
#pragma unroll
                for (int j = 0; j < 4; j++)
                    o[i][j] = fmaf(a[i], b[j], o[i][j]);
        }
        __syncthreads();
    }

    // epilogue: normalize and write token-major [B,N,DIM], channel = h*64+d
#pragma unroll
    for (int i = 0; i < 4; i++) {
        int row = q0 + ty * 4 + i;
        float inv = 1.0f / l_i[i];
#pragma unroll
        for (int j = 0; j < 4; j++) {
            O[((size_t)(bb * 2048 + row)) * 1024 + h * 64 + tx * 4 + j] =
                o[i][j] * inv;
        }
    }
}

extern "C" void kernel_launch(void* const* d_in, const int* in_sizes, int n_in,
                              void* d_out, int out_size, void* d_ws, size_t ws_size,
                              hipStream_t stream) {
    const float* x      = (const float*)d_in[0];
    const float* qkv_w  = (const float*)d_in[1];
    const float* qkv_b  = (const float*)d_in[2];
    const float* proj_w = (const float*)d_in[3];
    const float* proj_b = (const float*)d_in[4];
    float* out = (float*)d_out;

    const size_t per = (size_t)2 * 16 * 2048 * 64;  // 4,194,304 floats
    float* q  = (float*)d_ws;
    float* k  = q + per;
    float* v  = k + per;
    float* ao = v + per;

    dim3 blk(256);
    // qkv: M=4096 (y=64 tiles), NC=3072 (x=48 tiles)
    gemm_qkv_kernel<<<dim3(48, 64), blk, 0, stream>>>(x, qkv_w, qkv_b, q, k, v);
    // attention: (N/64=32, H=16, B=2)
    attn_kernel<<<dim3(32, 16, 2), blk, 0, stream>>>(q, k, v, ao);
    // proj: M=4096 (y=64), NC=1024 (x=16)
    gemm_proj_kernel<<<dim3(16, 64), blk, 0, stream>>>(ao, proj_w, proj_b, out);
}

// Round 3
// 622.393 us; speedup vs baseline: 2.1226x; 2.1226x over previous
//
#include <hip/hip_runtime.h>
#include <hip/hip_bf16.h>
#include <math.h>

// B=2, N=2048, DIM=1024, H=16, D=64; tokens M=4096; BH=32
typedef __attribute__((ext_vector_type(8))) short short8v;   // 8 bf16
typedef __attribute__((ext_vector_type(4))) float f32x4;

// ---------------------------------------------------------------------------
// QKV GEMM (f32 compute): C[M][3072] = A[M][1024] @ W[3072][1024]^T + bias.
// Epilogue: Q scaled by 1/8, emitted bf16 [BH][N][64]; K bf16 [BH][N][64];
// V bf16 TRANSPOSED [BH][64][N] (so attention PV B-fragments are contiguous).
// ---------------------------------------------------------------------------
__global__ __launch_bounds__(256) void gemm_qkv_kernel(
    const float* __restrict__ A, const float* __restrict__ W,
    const float* __restrict__ bias, __hip_bfloat16* __restrict__ Qb,
    __hip_bfloat16* __restrict__ Kb, __hip_bfloat16* __restrict__ Vt)
{
    __shared__ __align__(16) float Ast[16][68];
    __shared__ __align__(16) float Wst[16][68];
    const int t = threadIdx.x;
    const int tx = t & 15, ty = t >> 4;
    const int m0 = blockIdx.y * 64;
    const int n0 = blockIdx.x * 64;
    float acc[4][4] = {};

    for (int k0 = 0; k0 < 1024; k0 += 16) {
#pragma unroll
        for (int i = 0; i < 4; i++) {
            int idx = i * 256 + t;
            int r = idx >> 4, c = idx & 15;
            Ast[c][r] = A[(size_t)(m0 + r) * 1024 + k0 + c];
            Wst[c][r] = W[(size_t)(n0 + r) * 1024 + k0 + c];
        }
        __syncthreads();
#pragma unroll
        for (int kk = 0; kk < 16; kk++) {
            float4 a4 = *reinterpret_cast<const float4*>(&Ast[kk][ty * 4]);
            float4 b4 = *reinterpret_cast<const float4*>(&Wst[kk][tx * 4]);
            float a[4] = {a4.x, a4.y, a4.z, a4.w};
            float b[4] = {b4.x, b4.y, b4.z, b4.w};
#pragma unroll
            for (int i = 0; i < 4; i++)
#pragma unroll
                for (int j = 0; j < 4; j++)
                    acc[i][j] = fmaf(a[i], b[j], acc[i][j]);
        }
        __syncthreads();
    }

#pragma unroll
    for (int i = 0; i < 4; i++) {
        int row = m0 + ty * 4 + i;
        int bb = row >> 11, n = row & 2047;
#pragma unroll
        for (int j = 0; j < 4; j++) {
            int col = n0 + tx * 4 + j;
            float val = acc[i][j] + bias[col];
            int which = col >> 10;
            int rem = col & 1023;
            int h = rem >> 6, d = rem & 63;
            int bh = bb * 16 + h;
            if (which == 0)
                Qb[((size_t)bh * 2048 + n) * 64 + d] = __float2bfloat16(val * 0.125f);
            else if (which == 1)
                Kb[((size_t)bh * 2048 + n) * 64 + d] = __float2bfloat16(val);
            else
                Vt[((size_t)bh * 64 + d) * 2048 + n] = __float2bfloat16(val);
        }
    }
}

__global__ __launch_bounds__(256) void gemm_proj_kernel(
    const float* __restrict__ A, const float* __restrict__ W,
    const float* __restrict__ bias, float* __restrict__ C)
{
    __shared__ __align__(16) float Ast[16][68];
    __shared__ __align__(16) float Wst[16][68];
    const int t = threadIdx.x;
    const int tx = t & 15, ty = t >> 4;
    const int m0 = blockIdx.y * 64;
    const int n0 = blockIdx.x * 64;
    float acc[4][4] = {};

    for (int k0 = 0; k0 < 1024; k0 += 16) {
#pragma unroll
        for (int i = 0; i < 4; i++) {
            int idx = i * 256 + t;
            int r = idx >> 4, c = idx & 15;
            Ast[c][r] = A[(size_t)(m0 + r) * 1024 + k0 + c];
            Wst[c][r] = W[(size_t)(n0 + r) * 1024 + k0 + c];
        }
        __syncthreads();
#pragma unroll
        for (int kk = 0; kk < 16; kk++) {
            float4 a4 = *reinterpret_cast<const float4*>(&Ast[kk][ty * 4]);
            float4 b4 = *reinterpret_cast<const float4*>(&Wst[kk][tx * 4]);
            float a[4] = {a4.x, a4.y, a4.z, a4.w};
            float b[4] = {b4.x, b4.y, b4.z, b4.w};
#pragma unroll
            for (int i = 0; i < 4; i++)
#pragma unroll
                for (int j = 0; j < 4; j++)
                    acc[i][j] = fmaf(a[i], b[j], acc[i][j]);
        }
        __syncthreads();
    }

#pragma unroll
    for (int i = 0; i < 4; i++) {
        int row = m0 + ty * 4 + i;
#pragma unroll
        for (int j = 0; j < 4; j++) {
            int col = n0 + tx * 4 + j;
            C[(size_t)row * 1024 + col] = acc[i][j] + bias[col];
        }
    }
}

// ---------------------------------------------------------------------------
// MFMA flash attention. grid=(N/64, BH), block=256 (4 waves x 16 q-rows).
// 16x16x32 bf16 MFMA. K/V/P tiles in XOR-swizzled LDS (slot ^= row&7 of 16B
// slots within each 128B row) to kill the stride-128B bank conflict.
// Fragment maps (verified, guide §3): A row=lane&15, k=(lane>>4)*8+j;
// B col=lane&15, k=(lane>>4)*8+j; C/D col=lane&15, row=(lane>>4)*4+reg.
// ---------------------------------------------------------------------------
__global__ __launch_bounds__(256) void attn_mfma_kernel(
    const __hip_bfloat16* __restrict__ Qb, const __hip_bfloat16* __restrict__ Kb,
    const __hip_bfloat16* __restrict__ Vt, float* __restrict__ O)
{
    __shared__ __align__(16) unsigned short Ks[64 * 64];  // [kcol][d]
    __shared__ __align__(16) unsigned short Vs[64 * 64];  // [d][k]
    __shared__ __align__(16) unsigned short Ps[64 * 64];  // [q][k]

    const int t = threadIdx.x;
    const int l = t & 63, w = t >> 6;
    const int lo = l & 15, hi = l >> 4;  // hi in 0..3
    const int q0 = blockIdx.x * 64;
    const int bh = blockIdx.y;
    const unsigned short* Qg = (const unsigned short*)Qb + (size_t)bh * 2048 * 64;
    const unsigned short* Kg = (const unsigned short*)Kb + (size_t)bh * 2048 * 64;
    const unsigned short* Vg = (const unsigned short*)Vt + (size_t)bh * 64 * 2048;

    // Q A-fragments, loaded once: row = q0 + w*16 + lo, d = kk*32 + hi*8 + j
    short8v aq[2];
    {
        const unsigned short* qrow = Qg + (size_t)(q0 + w * 16 + lo) * 64;
        aq[0] = *(const short8v*)(qrow + hi * 8);
        aq[1] = *(const short8v*)(qrow + 32 + hi * 8);
    }

    f32x4 o_acc[4] = {};
    float m_i[4], l_i[4];
#pragma unroll
    for (int r = 0; r < 4; r++) { m_i[r] = -INFINITY; l_i[r] = 0.0f; }

    for (int kt = 0; kt < 32; kt++) {
        const int k0 = kt * 64;
        // stage K,V: 512 16B-chunks each; swizzled LDS slot = g ^ (row&7)
#pragma unroll
        for (int i = 0; i < 2; i++) {
            int idx = i * 256 + t;
            int r = idx >> 3, g = idx & 7;
            int gs = g ^ (r & 7);
            *(short8v*)&Ks[r * 64 + gs * 8] =
                *(const short8v*)(Kg + (size_t)(k0 + r) * 64 + g * 8);
            *(short8v*)&Vs[r * 64 + gs * 8] =
                *(const short8v*)(Vg + (size_t)r * 2048 + k0 + g * 8);
        }
        __syncthreads();

        // S = Q @ K^T : 4 n-tiles of 16 kcols, K-dim 64 = 2 chunks
        f32x4 s_acc[4];
        __builtin_amdgcn_s_setprio(1);
#pragma unroll
        for (int nt = 0; nt < 4; nt++) {
            f32x4 acc = {0.f, 0.f, 0.f, 0.f};
#pragma unroll
            for (int kk = 0; kk < 2; kk++) {
                int r = nt * 16 + lo;
                int g = (kk * 4 + hi) ^ (r & 7);
                short8v bk = *(const short8v*)&Ks[r * 64 + g * 8];
                acc = __builtin_amdgcn_mfma_f32_16x16x32_bf16(aq[kk], bk, acc, 0, 0, 0);
            }
            s_acc[nt] = acc;
        }
        __builtin_amdgcn_s_setprio(0);

        // online softmax; lane owns rows (hi*4+reg), cols nt*16+lo
        float alpha[4];
#pragma unroll
        for (int reg = 0; reg < 4; reg++) {
            float tm = fmaxf(fmaxf(s_acc[0][reg], s_acc[1][reg]),
                             fmaxf(s_acc[2][reg], s_acc[3][reg]));
#pragma unroll
            for (int sh = 1; sh < 16; sh <<= 1)
                tm = fmaxf(tm, __shfl_xor(tm, sh));
            float mnew = fmaxf(m_i[reg], tm);
            float al = __expf(m_i[reg] - mnew);
            float ps = 0.0f;
            int R = w * 16 + hi * 4 + reg;
#pragma unroll
            for (int nt = 0; nt < 4; nt++) {
                float p = __expf(s_acc[nt][reg] - mnew);
                ps += p;
                int c = nt * 16 + lo;
                int g = (c >> 3) ^ (R & 7);
                __hip_bfloat16 pb = __float2bfloat16(p);
                Ps[R * 64 + g * 8 + (c & 7)] = *(unsigned short*)&pb;
            }
#pragma unroll
            for (int sh = 1; sh < 16; sh <<= 1)
                ps += __shfl_xor(ps, sh);
            l_i[reg] = l_i[reg] * al + ps;
            m_i[reg] = mnew;
            alpha[reg] = al;
        }
#pragma unroll
        for (int dt = 0; dt < 4; dt++)
#pragma unroll
            for (int reg = 0; reg < 4; reg++)
                o_acc[dt][reg] *= alpha[reg];
        __syncthreads();

        // O += P @ V : A = P[16q][64k] (row = w*16+lo), B from Vs[d][k]
        short8v pa[2];
        {
            int R = w * 16 + lo;
            pa[0] = *(const short8v*)&Ps[R * 64 + ((0 + hi) ^ (R & 7)) * 8];
            pa[1] = *(const short8v*)&Ps[R * 64 + ((4 + hi) ^ (R & 7)) * 8];
        }
        __builtin_amdgcn_s_setprio(1);
#pragma unroll
        for (int dt = 0; dt < 4; dt++) {
            int r = dt * 16 + lo;
            short8v bv0 = *(const short8v*)&Vs[r * 64 + ((0 + hi) ^ (r & 7)) * 8];
            short8v bv1 = *(const short8v*)&Vs[r * 64 + ((4 + hi) ^ (r & 7)) * 8];
            o_acc[dt] = __builtin_amdgcn_mfma_f32_16x16x32_bf16(pa[0], bv0, o_acc[dt], 0, 0, 0);
            o_acc[dt] = __builtin_amdgcn_mfma_f32_16x16x32_bf16(pa[1], bv1, o_acc[dt], 0, 0, 0);
        }
        __builtin_amdgcn_s_setprio(0);
        __syncthreads();
    }

    // epilogue: normalize, write f32 token-major [B,N,1024]
    const int b = bh >> 4, h = bh & 15;
#pragma unroll
    for (int reg = 0; reg < 4; reg++) {
        float inv = 1.0f / l_i[reg];
        int row = q0 + w * 16 + hi * 4 + reg;
        float* orow = O + ((size_t)(b * 2048 + row)) * 1024 + h * 64;
#pragma unroll
        for (int dt = 0; dt < 4; dt++)
            orow[dt * 16 + lo] = o_acc[dt][reg] * inv;
    }
}

extern "C" void kernel_launch(void* const* d_in, const int* in_sizes, int n_in,
                              void* d_out, int out_size, void* d_ws, size_t ws_size,
                              hipStream_t stream) {
    const float* x      = (const float*)d_in[0];
    const float* qkv_w  = (const float*)d_in[1];
    const float* qkv_b  = (const float*)d_in[2];
    const float* proj_w = (const float*)d_in[3];
    const float* proj_b = (const float*)d_in[4];
    float* out = (float*)d_out;

    const size_t per = (size_t)32 * 2048 * 64;  // 4,194,304 elems per tensor
    __hip_bfloat16* qb = (__hip_bfloat16*)d_ws;
    __hip_bfloat16* kb = qb + per;
    __hip_bfloat16* vt = kb + per;
    float* ao = (float*)(vt + per);  // byte offset 3*per*2 = 25165824 (16B aligned)

    dim3 blk(256);
    gemm_qkv_kernel<<<dim3(48, 64), blk, 0, stream>>>(x, qkv_w, qkv_b, qb, kb, vt);
    attn_mfma_kernel<<<dim3(32, 32), blk, 0, stream>>>(qb, kb, vt, ao);
    gemm_proj_kernel<<<dim3(16, 64), blk, 0, stream>>>(ao, proj_w, proj_b, out);
}

// Round 4
// 176.638 us; speedup vs baseline: 7.4791x; 3.5236x over previous
//
#include <hip/hip_runtime.h>
#include <hip/hip_bf16.h>
#include <math.h>

// B=2, N=2048, DIM=1024, H=16, D=64; tokens M=4096; BH=32; K=1024
typedef __attribute__((ext_vector_type(8))) short short8v;   // 8 bf16
typedef __attribute__((ext_vector_type(4))) float f32x4;
typedef unsigned short ushort_t;

__device__ __forceinline__ ushort_t to_bf16(float v) {
    __hip_bfloat16 h = __float2bfloat16(v);
    return *(ushort_t*)&h;
}

__device__ __forceinline__ void load_lds_16B(const void* g, void* l) {
    __builtin_amdgcn_global_load_lds(
        (__attribute__((address_space(1))) unsigned int*)(g),
        (__attribute__((address_space(3))) unsigned int*)(l), 16, 0, 0);
}

// ---------------------------------------------------------------------------
// Fused f32 -> bf16 conversion of x (4.19M), qkv_w (3.15M), proj_w (1.05M).
// 1,048,576 chunks of 8 floats; grid 4096 x 256 exact.
// ---------------------------------------------------------------------------
__global__ __launch_bounds__(256) void convert_kernel(
    const float* __restrict__ x, const float* __restrict__ wq,
    const float* __restrict__ wp, ushort_t* __restrict__ xb,
    ushort_t* __restrict__ wqb, ushort_t* __restrict__ wpb)
{
    int c = blockIdx.x * 256 + threadIdx.x;
    const float* src; ushort_t* dst; int base;
    if (c < 524288)      { src = x;  dst = xb;  base = c; }
    else if (c < 917504) { src = wq; dst = wqb; base = c - 524288; }
    else                 { src = wp; dst = wpb; base = c - 917504; }
    const float4* s4 = (const float4*)src;
    float4 a = s4[2 * (size_t)base], b = s4[2 * (size_t)base + 1];
    float vals[8] = {a.x, a.y, a.z, a.w, b.x, b.y, b.z, b.w};
    short8v o;
#pragma unroll
    for (int j = 0; j < 8; j++) o[j] = (short)to_bf16(vals[j]);
    *(short8v*)(dst + 8 * (size_t)base) = o;
}

// ---------------------------------------------------------------------------
// bf16 MFMA GEMM, m97 structure: tile BMxBN, BK=32, 256 thr (4 waves, 2x2),
// global_load_lds width=16 staging, 2-barrier K-loop, 16x16x32 MFMA.
// C[M][NC] = A[M][1024] @ W[NC][1024]^T + bias.
// MODE 0: scatter bf16 Q(x0.125)/K -> [BH][N][64], V -> transposed [BH][64][N].
// MODE 1: f32 C[M][1024] = attention_out @ proj_w^T + bias.
// ---------------------------------------------------------------------------
template <int MODE, int BM, int BN>
__global__ __launch_bounds__(256) void gemm_bf16_kernel(
    const ushort_t* __restrict__ A, const ushort_t* __restrict__ Bw,
    const float* __restrict__ bias, ushort_t* __restrict__ Qb,
    ushort_t* __restrict__ Kb, ushort_t* __restrict__ Vt,
    float* __restrict__ Cout)
{
    constexpr int MT = BM / 32, NT = BN / 32;
    __shared__ __align__(16) ushort_t As[BM * 32];
    __shared__ __align__(16) ushort_t Bs[BN * 32];
    const int t = threadIdx.x;
    const int w = t >> 6, l = t & 63;
    const int lo = l & 15, hi = l >> 4;
    const int wr = w >> 1, wc = w & 1;
    const int m0 = blockIdx.y * BM, n0 = blockIdx.x * BN;
    const int K = 1024;

    // staging: chunk c = i*256 + t -> row = c>>2, col8 = (c&3)*8 (linear LDS)
    const ushort_t* ga = A + (size_t)(m0 + (t >> 2)) * K + (t & 3) * 8;
    const ushort_t* gb = Bw + (size_t)(n0 + (t >> 2)) * K + (t & 3) * 8;

    f32x4 acc[MT][NT] = {};

    for (int k0 = 0; k0 < 1024; k0 += 32) {
#pragma unroll
        for (int i = 0; i < BM / 64; i++)
            load_lds_16B(ga + (size_t)(i * 64) * K + k0, As + (i * 256 + w * 64) * 8);
#pragma unroll
        for (int i = 0; i < BN / 64; i++)
            load_lds_16B(gb + (size_t)(i * 64) * K + k0, Bs + (i * 256 + w * 64) * 8);
        __syncthreads();

        short8v af[MT], bf[NT];
#pragma unroll
        for (int mt = 0; mt < MT; mt++) {
            int r = wr * (BM / 2) + mt * 16 + lo;
            af[mt] = *(const short8v*)&As[r * 32 + hi * 8];
        }
#pragma unroll
        for (int nt = 0; nt < NT; nt++) {
            int r = wc * (BN / 2) + nt * 16 + lo;
            bf[nt] = *(const short8v*)&Bs[r * 32 + hi * 8];
        }
#pragma unroll
        for (int mt = 0; mt < MT; mt++)
#pragma unroll
            for (int nt = 0; nt < NT; nt++)
                acc[mt][nt] = __builtin_amdgcn_mfma_f32_16x16x32_bf16(
                    af[mt], bf[nt], acc[mt][nt], 0, 0, 0);
        __syncthreads();
    }

    // epilogue: C/D map col=lane&15, row=(lane>>4)*4+reg (verified)
#pragma unroll
    for (int mt = 0; mt < MT; mt++) {
#pragma unroll
        for (int nt = 0; nt < NT; nt++) {
            int col = n0 + wc * (BN / 2) + nt * 16 + lo;
            float bv = bias[col];
#pragma unroll
            for (int reg = 0; reg < 4; reg++) {
                int row = m0 + wr * (BM / 2) + mt * 16 + hi * 4 + reg;
                float val = acc[mt][nt][reg] + bv;
                if constexpr (MODE == 0) {
                    int bb = row >> 11, n = row & 2047;
                    int which = col >> 10, rem = col & 1023;
                    int h = rem >> 6, d = rem & 63;
                    int bh = bb * 16 + h;
                    if (which == 0)
                        Qb[((size_t)bh * 2048 + n) * 64 + d] = to_bf16(val * 0.125f);
                    else if (which == 1)
                        Kb[((size_t)bh * 2048 + n) * 64 + d] = to_bf16(val);
                    else
                        Vt[((size_t)bh * 64 + d) * 2048 + n] = to_bf16(val);
                } else {
                    Cout[(size_t)row * 1024 + col] = val;
                }
            }
        }
    }
}

// ---------------------------------------------------------------------------
// MFMA flash attention (validated round 2). grid=(N/64, BH), 4 waves x 16 rows.
// Epilogue now writes bf16 (A-operand of the proj GEMM).
// ---------------------------------------------------------------------------
__global__ __launch_bounds__(256) void attn_mfma_kernel(
    const ushort_t* __restrict__ Qg0, const ushort_t* __restrict__ Kg0,
    const ushort_t* __restrict__ Vg0, ushort_t* __restrict__ O)
{
    __shared__ __align__(16) ushort_t Ks[64 * 64];  // [kcol][d] swizzled
    __shared__ __align__(16) ushort_t Vs[64 * 64];  // [d][k] swizzled
    __shared__ __align__(16) ushort_t Ps[64 * 64];  // [q][k] swizzled

    const int t = threadIdx.x;
    const int l = t & 63, w = t >> 6;
    const int lo = l & 15, hi = l >> 4;
    const int q0 = blockIdx.x * 64;
    const int bh = blockIdx.y;
    const ushort_t* Qg = Qg0 + (size_t)bh * 2048 * 64;
    const ushort_t* Kg = Kg0 + (size_t)bh * 2048 * 64;
    const ushort_t* Vg = Vg0 + (size_t)bh * 64 * 2048;

    short8v aq[2];
    {
        const ushort_t* qrow = Qg + (size_t)(q0 + w * 16 + lo) * 64;
        aq[0] = *(const short8v*)(qrow + hi * 8);
        aq[1] = *(const short8v*)(qrow + 32 + hi * 8);
    }

    f32x4 o_acc[4] = {};
    float m_i[4], l_i[4];
#pragma unroll
    for (int r = 0; r < 4; r++) { m_i[r] = -INFINITY; l_i[r] = 0.0f; }

    for (int kt = 0; kt < 32; kt++) {
        const int k0 = kt * 64;
#pragma unroll
        for (int i = 0; i < 2; i++) {
            int idx = i * 256 + t;
            int r = idx >> 3, g = idx & 7;
            int gs = g ^ (r & 7);
            *(short8v*)&Ks[r * 64 + gs * 8] =
                *(const short8v*)(Kg + (size_t)(k0 + r) * 64 + g * 8);
            *(short8v*)&Vs[r * 64 + gs * 8] =
                *(const short8v*)(Vg + (size_t)r * 2048 + k0 + g * 8);
        }
        __syncthreads();

        f32x4 s_acc[4];
        __builtin_amdgcn_s_setprio(1);
#pragma unroll
        for (int nt = 0; nt < 4; nt++) {
            f32x4 acc = {0.f, 0.f, 0.f, 0.f};
#pragma unroll
            for (int kk = 0; kk < 2; kk++) {
                int r = nt * 16 + lo;
                int g = (kk * 4 + hi) ^ (r & 7);
                short8v bk = *(const short8v*)&Ks[r * 64 + g * 8];
                acc = __builtin_amdgcn_mfma_f32_16x16x32_bf16(aq[kk], bk, acc, 0, 0, 0);
            }
            s_acc[nt] = acc;
        }
        __builtin_amdgcn_s_setprio(0);

        float alpha[4];
#pragma unroll
        for (int reg = 0; reg < 4; reg++) {
            float tm = fmaxf(fmaxf(s_acc[0][reg], s_acc[1][reg]),
                             fmaxf(s_acc[2][reg], s_acc[3][reg]));
#pragma unroll
            for (int sh = 1; sh < 16; sh <<= 1)
                tm = fmaxf(tm, __shfl_xor(tm, sh));
            float mnew = fmaxf(m_i[reg], tm);
            float al = __expf(m_i[reg] - mnew);
            float ps = 0.0f;
            int R = w * 16 + hi * 4 + reg;
#pragma unroll
            for (int nt = 0; nt < 4; nt++) {
                float p = __expf(s_acc[nt][reg] - mnew);
                ps += p;
                int c = nt * 16 + lo;
                int g = (c >> 3) ^ (R & 7);
                Ps[R * 64 + g * 8 + (c & 7)] = to_bf16(p);
            }
#pragma unroll
            for (int sh = 1; sh < 16; sh <<= 1)
                ps += __shfl_xor(ps, sh);
            l_i[reg] = l_i[reg] * al + ps;
            m_i[reg] = mnew;
            alpha[reg] = al;
        }
#pragma unroll
        for (int dt = 0; dt < 4; dt++)
#pragma unroll
            for (int reg = 0; reg < 4; reg++)
                o_acc[dt][reg] *= alpha[reg];
        __syncthreads();

        short8v pa[2];
        {
            int R = w * 16 + lo;
            pa[0] = *(const short8v*)&Ps[R * 64 + ((0 + hi) ^ (R & 7)) * 8];
            pa[1] = *(const short8v*)&Ps[R * 64 + ((4 + hi) ^ (R & 7)) * 8];
        }
        __builtin_amdgcn_s_setprio(1);
#pragma unroll
        for (int dt = 0; dt < 4; dt++) {
            int r = dt * 16 + lo;
            short8v bv0 = *(const short8v*)&Vs[r * 64 + ((0 + hi) ^ (r & 7)) * 8];
            short8v bv1 = *(const short8v*)&Vs[r * 64 + ((4 + hi) ^ (r & 7)) * 8];
            o_acc[dt] = __builtin_amdgcn_mfma_f32_16x16x32_bf16(pa[0], bv0, o_acc[dt], 0, 0, 0);
            o_acc[dt] = __builtin_amdgcn_mfma_f32_16x16x32_bf16(pa[1], bv1, o_acc[dt], 0, 0, 0);
        }
        __builtin_amdgcn_s_setprio(0);
        __syncthreads();
    }

    const int b = bh >> 4, h = bh & 15;
#pragma unroll
    for (int reg = 0; reg < 4; reg++) {
        float inv = 1.0f / l_i[reg];
        int row = q0 + w * 16 + hi * 4 + reg;
        ushort_t* orow = O + ((size_t)(b * 2048 + row)) * 1024 + h * 64;
#pragma unroll
        for (int dt = 0; dt < 4; dt++)
            orow[dt * 16 + lo] = to_bf16(o_acc[dt][reg] * inv);
    }
}

extern "C" void kernel_launch(void* const* d_in, const int* in_sizes, int n_in,
                              void* d_out, int out_size, void* d_ws, size_t ws_size,
                              hipStream_t stream) {
    const float* x      = (const float*)d_in[0];
    const float* qkv_w  = (const float*)d_in[1];
    const float* qkv_b  = (const float*)d_in[2];
    const float* proj_w = (const float*)d_in[3];
    const float* proj_b = (const float*)d_in[4];
    float* out = (float*)d_out;

    // workspace layout (ushorts): total ~50.3 MB
    ushort_t* xb  = (ushort_t*)d_ws;        // 4,194,304  x bf16
    ushort_t* wqb = xb  + 4194304;          // 3,145,728  qkv_w bf16
    ushort_t* wpb = wqb + 3145728;          // 1,048,576  proj_w bf16
    ushort_t* qb  = wpb + 1048576;          // 4,194,304  Q [BH][N][64] (x0.125)
    ushort_t* kb  = qb  + 4194304;          // 4,194,304  K [BH][N][64]
    ushort_t* vt  = kb  + 4194304;          // 4,194,304  V^T [BH][64][N]
    ushort_t* aob = vt  + 4194304;          // 4,194,304  attn out [M][1024]

    convert_kernel<<<4096, 256, 0, stream>>>(x, qkv_w, proj_w, xb, wqb, wpb);
    gemm_bf16_kernel<0, 128, 128><<<dim3(24, 32), 256, 0, stream>>>(
        xb, wqb, qkv_b, qb, kb, vt, nullptr);
    attn_mfma_kernel<<<dim3(32, 32), 256, 0, stream>>>(qb, kb, vt, aob);
    gemm_bf16_kernel<1, 64, 64><<<dim3(16, 64), 256, 0, stream>>>(
        aob, wpb, proj_b, nullptr, nullptr, nullptr, out);
}

// Round 5
// 148.531 us; speedup vs baseline: 8.8944x; 1.1892x over previous
//
#include <hip/hip_runtime.h>
#include <hip/hip_bf16.h>
#include <math.h>

// B=2, N=2048, DIM=1024, H=16, D=64; tokens M=4096; BH=32; K=1024
typedef __attribute__((ext_vector_type(8))) short short8v;     // 8 bf16
typedef __attribute__((ext_vector_type(4))) float f32x4;
typedef __attribute__((ext_vector_type(4))) unsigned short ushort4v;
typedef unsigned short ushort_t;

__device__ __forceinline__ ushort_t to_bf16(float v) {
    __hip_bfloat16 h = __float2bfloat16(v);
    return *(ushort_t*)&h;
}

__device__ __forceinline__ void load_lds_16B(const void* g, void* l) {
    __builtin_amdgcn_global_load_lds(
        (__attribute__((address_space(1))) unsigned int*)(g),
        (__attribute__((address_space(3))) unsigned int*)(l), 16, 0, 0);
}

// ---------------------------------------------------------------------------
// Fused f32 -> bf16 conversion of x (4.19M), qkv_w (3.15M), proj_w (1.05M).
// ---------------------------------------------------------------------------
__global__ __launch_bounds__(256) void convert_kernel(
    const float* __restrict__ x, const float* __restrict__ wq,
    const float* __restrict__ wp, ushort_t* __restrict__ xb,
    ushort_t* __restrict__ wqb, ushort_t* __restrict__ wpb)
{
    int c = blockIdx.x * 256 + threadIdx.x;
    const float* src; ushort_t* dst; int base;
    if (c < 524288)      { src = x;  dst = xb;  base = c; }
    else if (c < 917504) { src = wq; dst = wqb; base = c - 524288; }
    else                 { src = wp; dst = wpb; base = c - 917504; }
    const float4* s4 = (const float4*)src;
    float4 a = s4[2 * (size_t)base], b = s4[2 * (size_t)base + 1];
    float vals[8] = {a.x, a.y, a.z, a.w, b.x, b.y, b.z, b.w};
    short8v o;
#pragma unroll
    for (int j = 0; j < 8; j++) o[j] = (short)to_bf16(vals[j]);
    *(short8v*)(dst + 8 * (size_t)base) = o;
}

// ---------------------------------------------------------------------------
// bf16 MFMA GEMM, m97 structure (unchanged from round 3).
// MODE 0: Q scaled by 0.125*log2(e) (exp2-domain softmax), K, V^T scatter.
// MODE 1: f32 C = A @ W^T + bias.
// ---------------------------------------------------------------------------
template <int MODE, int BM, int BN>
__global__ __launch_bounds__(256) void gemm_bf16_kernel(
    const ushort_t* __restrict__ A, const ushort_t* __restrict__ Bw,
    const float* __restrict__ bias, ushort_t* __restrict__ Qb,
    ushort_t* __restrict__ Kb, ushort_t* __restrict__ Vt,
    float* __restrict__ Cout)
{
    constexpr int MT = BM / 32, NT = BN / 32;
    __shared__ __align__(16) ushort_t As[BM * 32];
    __shared__ __align__(16) ushort_t Bs[BN * 32];
    const int t = threadIdx.x;
    const int w = t >> 6, l = t & 63;
    const int lo = l & 15, hi = l >> 4;
    const int wr = w >> 1, wc = w & 1;
    const int m0 = blockIdx.y * BM, n0 = blockIdx.x * BN;
    const int K = 1024;

    const ushort_t* ga = A + (size_t)(m0 + (t >> 2)) * K + (t & 3) * 8;
    const ushort_t* gb = Bw + (size_t)(n0 + (t >> 2)) * K + (t & 3) * 8;

    f32x4 acc[MT][NT] = {};

    for (int k0 = 0; k0 < 1024; k0 += 32) {
#pragma unroll
        for (int i = 0; i < BM / 64; i++)
            load_lds_16B(ga + (size_t)(i * 64) * K + k0, As + (i * 256 + w * 64) * 8);
#pragma unroll
        for (int i = 0; i < BN / 64; i++)
            load_lds_16B(gb + (size_t)(i * 64) * K + k0, Bs + (i * 256 + w * 64) * 8);
        __syncthreads();

        short8v af[MT], bf[NT];
#pragma unroll
        for (int mt = 0; mt < MT; mt++) {
            int r = wr * (BM / 2) + mt * 16 + lo;
            af[mt] = *(const short8v*)&As[r * 32 + hi * 8];
        }
#pragma unroll
        for (int nt = 0; nt < NT; nt++) {
            int r = wc * (BN / 2) + nt * 16 + lo;
            bf[nt] = *(const short8v*)&Bs[r * 32 + hi * 8];
        }
#pragma unroll
        for (int mt = 0; mt < MT; mt++)
#pragma unroll
            for (int nt = 0; nt < NT; nt++)
                acc[mt][nt] = __builtin_amdgcn_mfma_f32_16x16x32_bf16(
                    af[mt], bf[nt], acc[mt][nt], 0, 0, 0);
        __syncthreads();
    }

#pragma unroll
    for (int mt = 0; mt < MT; mt++) {
#pragma unroll
        for (int nt = 0; nt < NT; nt++) {
            int col = n0 + wc * (BN / 2) + nt * 16 + lo;
            float bv = bias[col];
#pragma unroll
            for (int reg = 0; reg < 4; reg++) {
                int row = m0 + wr * (BM / 2) + mt * 16 + hi * 4 + reg;
                float val = acc[mt][nt][reg] + bv;
                if constexpr (MODE == 0) {
                    int bb = row >> 11, n = row & 2047;
                    int which = col >> 10, rem = col & 1023;
                    int h = rem >> 6, d = rem & 63;
                    int bh = bb * 16 + h;
                    if (which == 0)  // 0.125 * log2(e): softmax done in exp2 domain
                        Qb[((size_t)bh * 2048 + n) * 64 + d] = to_bf16(val * 0.1803368601f);
                    else if (which == 1)
                        Kb[((size_t)bh * 2048 + n) * 64 + d] = to_bf16(val);
                    else
                        Vt[((size_t)bh * 64 + d) * 2048 + n] = to_bf16(val);
                } else {
                    Cout[(size_t)row * 1024 + col] = val;
                }
            }
        }
    }
}

// ---------------------------------------------------------------------------
// MFMA flash attention v2. grid=(N/64, BH), 4 waves x 16 q-rows.
// Swapped QK^T (S^T = mfma(K,Q)): lane owns query lo -> per-lane m/l state,
// row-reduce = in-reg tree + 2 shfl. exp2-domain. Defer-max THR=11 (log2).
// K/V double-buffered LDS + async-stage split: 1 barrier per tile.
// P tile is wave-private (rows w*16+lo) -> no barrier around P.
// ---------------------------------------------------------------------------
__global__ __launch_bounds__(256) void attn_mfma_kernel(
    const ushort_t* __restrict__ Qg0, const ushort_t* __restrict__ Kg0,
    const ushort_t* __restrict__ Vg0, ushort_t* __restrict__ O)
{
    __shared__ __align__(16) ushort_t Ks[2][64 * 64];  // [kcol][d] swizzled
    __shared__ __align__(16) ushort_t Vs[2][64 * 64];  // [d][k] swizzled
    __shared__ __align__(16) ushort_t Ps[64 * 64];     // [q][k] swizzled

    const int t = threadIdx.x;
    const int l = t & 63, w = t >> 6;
    const int lo = l & 15, hi = l >> 4;
    const int q0 = blockIdx.x * 64;
    const int bh = blockIdx.y;
    const ushort_t* Qg = Qg0 + (size_t)bh * 2048 * 64;
    const ushort_t* Kg = Kg0 + (size_t)bh * 2048 * 64;
    const ushort_t* Vg = Vg0 + (size_t)bh * 64 * 2048;

    // Q fragment (acts as MFMA B-operand after the swap; same lane map)
    short8v aq[2];
    {
        const ushort_t* qrow = Qg + (size_t)(q0 + w * 16 + lo) * 64;
        aq[0] = *(const short8v*)(qrow + hi * 8);
        aq[1] = *(const short8v*)(qrow + 32 + hi * 8);
    }

    // staging: thread covers rows (t>>3) and (t>>3)+32, 16B chunk (t&7)
    const int srow = t >> 3, sg = t & 7;
    const int sgs = sg ^ (srow & 7);  // (srow+32)&7 == srow&7
    short8v rk0, rk1, rv0, rv1;

    f32x4 o_acc[4] = {};
    float m_i = -INFINITY, l_i = 0.0f;

    // prologue: stage tile 0 into buffer 0
    {
        rk0 = *(const short8v*)(Kg + (size_t)srow * 64 + sg * 8);
        rk1 = *(const short8v*)(Kg + (size_t)(srow + 32) * 64 + sg * 8);
        rv0 = *(const short8v*)(Vg + (size_t)srow * 2048 + sg * 8);
        rv1 = *(const short8v*)(Vg + (size_t)(srow + 32) * 2048 + sg * 8);
        *(short8v*)&Ks[0][srow * 64 + sgs * 8] = rk0;
        *(short8v*)&Ks[0][(srow + 32) * 64 + sgs * 8] = rk1;
        *(short8v*)&Vs[0][srow * 64 + sgs * 8] = rv0;
        *(short8v*)&Vs[0][(srow + 32) * 64 + sgs * 8] = rv1;
    }
    __syncthreads();

    for (int kt = 0; kt < 32; kt++) {
        const int cur = kt & 1;
        // async-stage: issue next tile's global loads now, LDS-write later
        if (kt < 31) {
            const int k0n = (kt + 1) * 64;
            rk0 = *(const short8v*)(Kg + (size_t)(k0n + srow) * 64 + sg * 8);
            rk1 = *(const short8v*)(Kg + (size_t)(k0n + srow + 32) * 64 + sg * 8);
            rv0 = *(const short8v*)(Vg + (size_t)srow * 2048 + k0n + sg * 8);
            rv1 = *(const short8v*)(Vg + (size_t)(srow + 32) * 2048 + k0n + sg * 8);
        }

        // S^T = K @ Q^T : lane holds query lo, keys nt*16 + hi*4 + reg
        f32x4 s_acc[4];
        __builtin_amdgcn_s_setprio(1);
#pragma unroll
        for (int nt = 0; nt < 4; nt++) {
            f32x4 acc = {0.f, 0.f, 0.f, 0.f};
#pragma unroll
            for (int kk = 0; kk < 2; kk++) {
                int r = nt * 16 + lo;
                int g = (kk * 4 + hi) ^ (r & 7);
                short8v ak = *(const short8v*)&Ks[cur][r * 64 + g * 8];
                acc = __builtin_amdgcn_mfma_f32_16x16x32_bf16(ak, aq[kk], acc, 0, 0, 0);
            }
            s_acc[nt] = acc;
        }
        __builtin_amdgcn_s_setprio(0);

        // per-lane softmax for query lo (16 values in-register)
        float pmax = -INFINITY;
#pragma unroll
        for (int nt = 0; nt < 4; nt++)
#pragma unroll
            for (int reg = 0; reg < 4; reg++)
                pmax = fmaxf(pmax, s_acc[nt][reg]);
        pmax = fmaxf(pmax, __shfl_xor(pmax, 16));
        pmax = fmaxf(pmax, __shfl_xor(pmax, 32));

        if (__any(pmax > m_i + 11.0f)) {  // defer-max: rarely taken after tile 0
            float mnew = fmaxf(m_i, pmax);
            float al = exp2f(m_i - mnew);
            m_i = mnew;
            l_i *= al;
            float a0 = __shfl(al, hi * 4 + 0);
            float a1 = __shfl(al, hi * 4 + 1);
            float a2 = __shfl(al, hi * 4 + 2);
            float a3 = __shfl(al, hi * 4 + 3);
#pragma unroll
            for (int dt = 0; dt < 4; dt++) {
                o_acc[dt][0] *= a0; o_acc[dt][1] *= a1;
                o_acc[dt][2] *= a2; o_acc[dt][3] *= a3;
            }
        }

        float p[4][4];
        float ps = 0.0f;
#pragma unroll
        for (int nt = 0; nt < 4; nt++)
#pragma unroll
            for (int reg = 0; reg < 4; reg++) {
                p[nt][reg] = exp2f(s_acc[nt][reg] - m_i);
                ps += p[nt][reg];
            }
        ps += __shfl_xor(ps, 16);
        ps += __shfl_xor(ps, 32);
        l_i += ps;

        // packed P writes: row R=w*16+lo, 4 consecutive keys per nt
        const int R = w * 16 + lo;
#pragma unroll
        for (int nt = 0; nt < 4; nt++) {
            int c0 = nt * 16 + hi * 4;
            int g = (c0 >> 3) ^ (R & 7);
            ushort4v pv = {to_bf16(p[nt][0]), to_bf16(p[nt][1]),
                           to_bf16(p[nt][2]), to_bf16(p[nt][3])};
            *(ushort4v*)&Ps[R * 64 + g * 8 + (c0 & 7)] = pv;
        }
        // same-wave cross-lane LDS ordering for Ps (wave-private tile)
        asm volatile("s_waitcnt lgkmcnt(0)" ::: "memory");
        short8v pa0 = *(const short8v*)&Ps[R * 64 + ((0 + hi) ^ (R & 7)) * 8];
        short8v pa1 = *(const short8v*)&Ps[R * 64 + ((4 + hi) ^ (R & 7)) * 8];

        // late LDS write of the prefetched tile (compiler inserts vmcnt waits)
        if (kt < 31) {
            const int nxt = cur ^ 1;
            *(short8v*)&Ks[nxt][srow * 64 + sgs * 8] = rk0;
            *(short8v*)&Ks[nxt][(srow + 32) * 64 + sgs * 8] = rk1;
            *(short8v*)&Vs[nxt][srow * 64 + sgs * 8] = rv0;
            *(short8v*)&Vs[nxt][(srow + 32) * 64 + sgs * 8] = rv1;
        }

        // O += P @ V
        __builtin_amdgcn_s_setprio(1);
#pragma unroll
        for (int dt = 0; dt < 4; dt++) {
            int r = dt * 16 + lo;
            short8v bv0 = *(const short8v*)&Vs[cur][r * 64 + ((0 + hi) ^ (r & 7)) * 8];
            short8v bv1 = *(const short8v*)&Vs[cur][r * 64 + ((4 + hi) ^ (r & 7)) * 8];
            o_acc[dt] = __builtin_amdgcn_mfma_f32_16x16x32_bf16(pa0, bv0, o_acc[dt], 0, 0, 0);
            o_acc[dt] = __builtin_amdgcn_mfma_f32_16x16x32_bf16(pa1, bv1, o_acc[dt], 0, 0, 0);
        }
        __builtin_amdgcn_s_setprio(0);
        __syncthreads();
    }

    // epilogue: normalize (broadcast l from the lane owning each query row)
    const int b = bh >> 4, h = bh & 15;
#pragma unroll
    for (int reg = 0; reg < 4; reg++) {
        float lv = __shfl(l_i, hi * 4 + reg);
        float inv = 1.0f / lv;
        int row = q0 + w * 16 + hi * 4 + reg;
        ushort_t* orow = O + ((size_t)(b * 2048 + row)) * 1024 + h * 64;
#pragma unroll
        for (int dt = 0; dt < 4; dt++)
            orow[dt * 16 + lo] = to_bf16(o_acc[dt][reg] * inv);
    }
}

extern "C" void kernel_launch(void* const* d_in, const int* in_sizes, int n_in,
                              void* d_out, int out_size, void* d_ws, size_t ws_size,
                              hipStream_t stream) {
    const float* x      = (const float*)d_in[0];
    const float* qkv_w  = (const float*)d_in[1];
    const float* qkv_b  = (const float*)d_in[2];
    const float* proj_w = (const float*)d_in[3];
    const float* proj_b = (const float*)d_in[4];
    float* out = (float*)d_out;

    ushort_t* xb  = (ushort_t*)d_ws;        // 4,194,304  x bf16
    ushort_t* wqb = xb  + 4194304;          // 3,145,728  qkv_w bf16
    ushort_t* wpb = wqb + 3145728;          // 1,048,576  proj_w bf16
    ushort_t* qb  = wpb + 1048576;          // 4,194,304  Q (exp2-scaled)
    ushort_t* kb  = qb  + 4194304;          // 4,194,304  K
    ushort_t* vt  = kb  + 4194304;          // 4,194,304  V^T [BH][64][N]
    ushort_t* aob = vt  + 4194304;          // 4,194,304  attn out [M][1024]

    convert_kernel<<<4096, 256, 0, stream>>>(x, qkv_w, proj_w, xb, wqb, wpb);
    gemm_bf16_kernel<0, 128, 128><<<dim3(24, 32), 256, 0, stream>>>(
        xb, wqb, qkv_b, qb, kb, vt, nullptr);
    attn_mfma_kernel<<<dim3(32, 32), 256, 0, stream>>>(qb, kb, vt, aob);
    gemm_bf16_kernel<1, 64, 64><<<dim3(16, 64), 256, 0, stream>>>(
        aob, wpb, proj_b, nullptr, nullptr, nullptr, out);
}

// Round 6
// 142.597 us; speedup vs baseline: 9.2646x; 1.0416x over previous
//
#include <hip/hip_runtime.h>
#include <hip/hip_bf16.h>
#include <math.h>

// B=2, N=2048, DIM=1024, H=16, D=64; tokens M=4096; BH=32; K=1024
typedef __attribute__((ext_vector_type(8))) short short8v;     // 8 bf16
typedef __attribute__((ext_vector_type(4))) float f32x4;
typedef unsigned short ushort_t;

__device__ __forceinline__ ushort_t to_bf16(float v) {
    __hip_bfloat16 h = __float2bfloat16(v);
    return *(ushort_t*)&h;
}

// packed f32x2 -> bf16x2 (RNE), single instruction
__device__ __forceinline__ unsigned cvt_pk_bf16(float a, float b) {
    unsigned r;
    asm("v_cvt_pk_bf16_f32 %0, %1, %2" : "=v"(r) : "v"(a), "v"(b));
    return r;
}

__device__ __forceinline__ void load_lds_16B(const void* g, void* l) {
    __builtin_amdgcn_global_load_lds(
        (__attribute__((address_space(1))) unsigned int*)(g),
        (__attribute__((address_space(3))) unsigned int*)(l), 16, 0, 0);
}

// ---------------------------------------------------------------------------
// Fused f32 -> bf16 conversion of x (4.19M), qkv_w (3.15M), proj_w (1.05M).
// ---------------------------------------------------------------------------
__global__ __launch_bounds__(256) void convert_kernel(
    const float* __restrict__ x, const float* __restrict__ wq,
    const float* __restrict__ wp, ushort_t* __restrict__ xb,
    ushort_t* __restrict__ wqb, ushort_t* __restrict__ wpb)
{
    int c = blockIdx.x * 256 + threadIdx.x;
    const float* src; ushort_t* dst; int base;
    if (c < 524288)      { src = x;  dst = xb;  base = c; }
    else if (c < 917504) { src = wq; dst = wqb; base = c - 524288; }
    else                 { src = wp; dst = wpb; base = c - 917504; }
    const float4* s4 = (const float4*)src;
    float4 a = s4[2 * (size_t)base], b = s4[2 * (size_t)base + 1];
    float vals[8] = {a.x, a.y, a.z, a.w, b.x, b.y, b.z, b.w};
    short8v o;
#pragma unroll
    for (int j = 0; j < 8; j++) o[j] = (short)to_bf16(vals[j]);
    *(short8v*)(dst + 8 * (size_t)base) = o;
}

// ---------------------------------------------------------------------------
// bf16 MFMA GEMM, m97 structure. MODE 0: Q(x0.125*log2e)/K/V^T scatter.
// MODE 1: f32 C = A @ W^T + bias.
// ---------------------------------------------------------------------------
template <int MODE, int BM, int BN>
__global__ __launch_bounds__(256) void gemm_bf16_kernel(
    const ushort_t* __restrict__ A, const ushort_t* __restrict__ Bw,
    const float* __restrict__ bias, ushort_t* __restrict__ Qb,
    ushort_t* __restrict__ Kb, ushort_t* __restrict__ Vt,
    float* __restrict__ Cout)
{
    constexpr int MT = BM / 32, NT = BN / 32;
    __shared__ __align__(16) ushort_t As[BM * 32];
    __shared__ __align__(16) ushort_t Bs[BN * 32];
    const int t = threadIdx.x;
    const int w = t >> 6, l = t & 63;
    const int lo = l & 15, hi = l >> 4;
    const int wr = w >> 1, wc = w & 1;
    const int m0 = blockIdx.y * BM, n0 = blockIdx.x * BN;
    const int K = 1024;

    const ushort_t* ga = A + (size_t)(m0 + (t >> 2)) * K + (t & 3) * 8;
    const ushort_t* gb = Bw + (size_t)(n0 + (t >> 2)) * K + (t & 3) * 8;

    f32x4 acc[MT][NT] = {};

    for (int k0 = 0; k0 < 1024; k0 += 32) {
#pragma unroll
        for (int i = 0; i < BM / 64; i++)
            load_lds_16B(ga + (size_t)(i * 64) * K + k0, As + (i * 256 + w * 64) * 8);
#pragma unroll
        for (int i = 0; i < BN / 64; i++)
            load_lds_16B(gb + (size_t)(i * 64) * K + k0, Bs + (i * 256 + w * 64) * 8);
        __syncthreads();

        short8v af[MT], bf[NT];
#pragma unroll
        for (int mt = 0; mt < MT; mt++) {
            int r = wr * (BM / 2) + mt * 16 + lo;
            af[mt] = *(const short8v*)&As[r * 32 + hi * 8];
        }
#pragma unroll
        for (int nt = 0; nt < NT; nt++) {
            int r = wc * (BN / 2) + nt * 16 + lo;
            bf[nt] = *(const short8v*)&Bs[r * 32 + hi * 8];
        }
#pragma unroll
        for (int mt = 0; mt < MT; mt++)
#pragma unroll
            for (int nt = 0; nt < NT; nt++)
                acc[mt][nt] = __builtin_amdgcn_mfma_f32_16x16x32_bf16(
                    af[mt], bf[nt], acc[mt][nt], 0, 0, 0);
        __syncthreads();
    }

#pragma unroll
    for (int mt = 0; mt < MT; mt++) {
#pragma unroll
        for (int nt = 0; nt < NT; nt++) {
            int col = n0 + wc * (BN / 2) + nt * 16 + lo;
            float bv = bias[col];
#pragma unroll
            for (int reg = 0; reg < 4; reg++) {
                int row = m0 + wr * (BM / 2) + mt * 16 + hi * 4 + reg;
                float val = acc[mt][nt][reg] + bv;
                if constexpr (MODE == 0) {
                    int bb = row >> 11, n = row & 2047;
                    int which = col >> 10, rem = col & 1023;
                    int h = rem >> 6, d = rem & 63;
                    int bh = bb * 16 + h;
                    if (which == 0)  // 0.125 * log2(e): softmax in exp2 domain
                        Qb[((size_t)bh * 2048 + n) * 64 + d] = to_bf16(val * 0.1803368601f);
                    else if (which == 1)
                        Kb[((size_t)bh * 2048 + n) * 64 + d] = to_bf16(val);
                    else
                        Vt[((size_t)bh * 64 + d) * 2048 + n] = to_bf16(val);
                } else {
                    Cout[(size_t)row * 1024 + col] = val;
                }
            }
        }
    }
}

// ---------------------------------------------------------------------------
// MFMA flash attention v3. grid = 1024 (1D, XCD-swizzled), 4 waves x 16 rows.
// Swapped QK^T, exp2 domain (raw v_exp_f32), defer-max THR=11, packed
// v_cvt_pk_bf16_f32 P-writes, K/V dbuf + async-stage split, 1 barrier/tile.
// XCD swizzle: each XCD owns 4 consecutive heads -> K/V stays in its L2.
// ---------------------------------------------------------------------------
__global__ __launch_bounds__(256) void attn_mfma_kernel(
    const ushort_t* __restrict__ Qg0, const ushort_t* __restrict__ Kg0,
    const ushort_t* __restrict__ Vg0, ushort_t* __restrict__ O)
{
    __shared__ __align__(16) ushort_t Ks[2 * 64 * 64];  // [buf][kcol][d] swz
    __shared__ __align__(16) ushort_t Vs[2 * 64 * 64];  // [buf][d][k] swz
    __shared__ __align__(16) ushort_t Ps[64 * 64];      // [q][k] swz

    const int t = threadIdx.x;
    const int l = t & 63, w = t >> 6;
    const int lo = l & 15, hi = l >> 4;
    // XCD-aware mapping: lin = (bid%8)*128 + bid/8; bh = lin>>5 (4 heads/XCD)
    const int lin = (blockIdx.x & 7) * 128 + (blockIdx.x >> 3);
    const int bh = lin >> 5;
    const int q0 = (lin & 31) * 64;
    const ushort_t* Qg = Qg0 + (size_t)bh * 2048 * 64;
    const ushort_t* Kg = Kg0 + (size_t)bh * 2048 * 64;
    const ushort_t* Vg = Vg0 + (size_t)bh * 64 * 2048;

    short8v aq[2];
    {
        const ushort_t* qrow = Qg + (size_t)(q0 + w * 16 + lo) * 64;
        aq[0] = *(const short8v*)(qrow + hi * 8);
        aq[1] = *(const short8v*)(qrow + 32 + hi * 8);
    }

    const int srow = t >> 3, sg = t & 7;
    const int sgs = sg ^ (srow & 7);
    short8v rk0, rk1, rv0, rv1;

    f32x4 o_acc[4] = {};
    float m_i = -INFINITY, l_i = 0.0f;

    {
        rk0 = *(const short8v*)(Kg + (size_t)srow * 64 + sg * 8);
        rk1 = *(const short8v*)(Kg + (size_t)(srow + 32) * 64 + sg * 8);
        rv0 = *(const short8v*)(Vg + (size_t)srow * 2048 + sg * 8);
        rv1 = *(const short8v*)(Vg + (size_t)(srow + 32) * 2048 + sg * 8);
        *(short8v*)&Ks[srow * 64 + sgs * 8] = rk0;
        *(short8v*)&Ks[(srow + 32) * 64 + sgs * 8] = rk1;
        *(short8v*)&Vs[srow * 64 + sgs * 8] = rv0;
        *(short8v*)&Vs[(srow + 32) * 64 + sgs * 8] = rv1;
    }
    __syncthreads();

    for (int kt = 0; kt < 32; kt++) {
        const int bufo = (kt & 1) * 4096;
        if (kt < 31) {
            const int k0n = (kt + 1) * 64;
            rk0 = *(const short8v*)(Kg + (size_t)(k0n + srow) * 64 + sg * 8);
            rk1 = *(const short8v*)(Kg + (size_t)(k0n + srow + 32) * 64 + sg * 8);
            rv0 = *(const short8v*)(Vg + (size_t)srow * 2048 + k0n + sg * 8);
            rv1 = *(const short8v*)(Vg + (size_t)(srow + 32) * 2048 + k0n + sg * 8);
        }

        // S^T = K @ Q^T : lane owns query lo; keys nt*16 + hi*4 + reg
        f32x4 s_acc[4];
        __builtin_amdgcn_s_setprio(1);
#pragma unroll
        for (int nt = 0; nt < 4; nt++) {
            f32x4 acc = {0.f, 0.f, 0.f, 0.f};
#pragma unroll
            for (int kk = 0; kk < 2; kk++) {
                int r = nt * 16 + lo;
                int g = (kk * 4 + hi) ^ (r & 7);
                short8v ak = *(const short8v*)&Ks[bufo + r * 64 + g * 8];
                acc = __builtin_amdgcn_mfma_f32_16x16x32_bf16(ak, aq[kk], acc, 0, 0, 0);
            }
            s_acc[nt] = acc;
        }
        __builtin_amdgcn_s_setprio(0);

        float pmax = fmaxf(
            fmaxf(fmaxf(fmaxf(s_acc[0][0], s_acc[0][1]), fmaxf(s_acc[0][2], s_acc[0][3])),
                  fmaxf(fmaxf(s_acc[1][0], s_acc[1][1]), fmaxf(s_acc[1][2], s_acc[1][3]))),
            fmaxf(fmaxf(fmaxf(s_acc[2][0], s_acc[2][1]), fmaxf(s_acc[2][2], s_acc[2][3])),
                  fmaxf(fmaxf(s_acc[3][0], s_acc[3][1]), fmaxf(s_acc[3][2], s_acc[3][3]))));
        pmax = fmaxf(pmax, __shfl_xor(pmax, 16));
        pmax = fmaxf(pmax, __shfl_xor(pmax, 32));

        if (__any(pmax > m_i + 11.0f)) {
            float mnew = fmaxf(m_i, pmax);
            float al = __builtin_amdgcn_exp2f(m_i - mnew);
            m_i = mnew;
            l_i *= al;
            float a0 = __shfl(al, hi * 4 + 0);
            float a1 = __shfl(al, hi * 4 + 1);
            float a2 = __shfl(al, hi * 4 + 2);
            float a3 = __shfl(al, hi * 4 + 3);
#pragma unroll
            for (int dt = 0; dt < 4; dt++) {
                o_acc[dt][0] *= a0; o_acc[dt][1] *= a1;
                o_acc[dt][2] *= a2; o_acc[dt][3] *= a3;
            }
        }

        float p[4][4];
        float ps = 0.0f;
#pragma unroll
        for (int nt = 0; nt < 4; nt++)
#pragma unroll
            for (int reg = 0; reg < 4; reg++) {
                p[nt][reg] = __builtin_amdgcn_exp2f(s_acc[nt][reg] - m_i);
                ps += p[nt][reg];
            }
        ps += __shfl_xor(ps, 16);
        ps += __shfl_xor(ps, 32);
        l_i += ps;

        // packed P writes: row R = w*16+lo, dword pair at col c0 = nt*16+hi*4
        const int R = w * 16 + lo;
#pragma unroll
        for (int nt = 0; nt < 4; nt++) {
            int c0 = nt * 16 + hi * 4;
            int g = (c0 >> 3) ^ (R & 7);
            uint2 pv = {cvt_pk_bf16(p[nt][0], p[nt][1]),
                        cvt_pk_bf16(p[nt][2], p[nt][3])};
            *(uint2*)&Ps[R * 64 + g * 8 + (c0 & 7)] = pv;
        }
        asm volatile("s_waitcnt lgkmcnt(0)" ::: "memory");
        short8v pa0 = *(const short8v*)&Ps[R * 64 + ((0 + hi) ^ (R & 7)) * 8];
        short8v pa1 = *(const short8v*)&Ps[R * 64 + ((4 + hi) ^ (R & 7)) * 8];

        if (kt < 31) {
            const int nxto = 4096 - bufo;
            *(short8v*)&Ks[nxto + srow * 64 + sgs * 8] = rk0;
            *(short8v*)&Ks[nxto + (srow + 32) * 64 + sgs * 8] = rk1;
            *(short8v*)&Vs[nxto + srow * 64 + sgs * 8] = rv0;
            *(short8v*)&Vs[nxto + (srow + 32) * 64 + sgs * 8] = rv1;
        }

        __builtin_amdgcn_s_setprio(1);
#pragma unroll
        for (int dt = 0; dt < 4; dt++) {
            int r = dt * 16 + lo;
            short8v bv0 = *(const short8v*)&Vs[bufo + r * 64 + ((0 + hi) ^ (r & 7)) * 8];
            short8v bv1 = *(const short8v*)&Vs[bufo + r * 64 + ((4 + hi) ^ (r & 7)) * 8];
            o_acc[dt] = __builtin_amdgcn_mfma_f32_16x16x32_bf16(pa0, bv0, o_acc[dt], 0, 0, 0);
            o_acc[dt] = __builtin_amdgcn_mfma_f32_16x16x32_bf16(pa1, bv1, o_acc[dt], 0, 0, 0);
        }
        __builtin_amdgcn_s_setprio(0);
        __syncthreads();
    }

    const int b = bh >> 4, h = bh & 15;
#pragma unroll
    for (int reg = 0; reg < 4; reg++) {
        float lv = __shfl(l_i, hi * 4 + reg);
        float inv = 1.0f / lv;
        int row = q0 + w * 16 + hi * 4 + reg;
        ushort_t* orow = O + ((size_t)(b * 2048 + row)) * 1024 + h * 64;
#pragma unroll
        for (int dt = 0; dt < 4; dt++)
            orow[dt * 16 + lo] = to_bf16(o_acc[dt][reg] * inv);
    }
}

extern "C" void kernel_launch(void* const* d_in, const int* in_sizes, int n_in,
                              void* d_out, int out_size, void* d_ws, size_t ws_size,
                              hipStream_t stream) {
    const float* x      = (const float*)d_in[0];
    const float* qkv_w  = (const float*)d_in[1];
    const float* qkv_b  = (const float*)d_in[2];
    const float* proj_w = (const float*)d_in[3];
    const float* proj_b = (const float*)d_in[4];
    float* out = (float*)d_out;

    ushort_t* xb  = (ushort_t*)d_ws;        // 4,194,304  x bf16
    ushort_t* wqb = xb  + 4194304;          // 3,145,728  qkv_w bf16
    ushort_t* wpb = wqb + 3145728;          // 1,048,576  proj_w bf16
    ushort_t* qb  = wpb + 1048576;          // 4,194,304  Q (exp2-scaled)
    ushort_t* kb  = qb  + 4194304;          // 4,194,304  K
    ushort_t* vt  = kb  + 4194304;          // 4,194,304  V^T [BH][64][N]
    ushort_t* aob = vt  + 4194304;          // 4,194,304  attn out [M][1024]

    convert_kernel<<<4096, 256, 0, stream>>>(x, qkv_w, proj_w, xb, wqb, wpb);
    gemm_bf16_kernel<0, 128, 128><<<dim3(24, 32), 256, 0, stream>>>(
        xb, wqb, qkv_b, qb, kb, vt, nullptr);
    attn_mfma_kernel<<<1024, 256, 0, stream>>>(qb, kb, vt, aob);
    gemm_bf16_kernel<1, 128, 128><<<dim3(8, 32), 256, 0, stream>>>(
        aob, wpb, proj_b, nullptr, nullptr, nullptr, out);
}